// Round 1
// baseline (150.987 us; speedup 1.0000x reference)
//
#include <hip/hip_runtime.h>
#include <hip/hip_bf16.h>

// SDDMM: out[n] = mask_vals[n] + dot(mat1[rows[n], :], mat2[:, cols[n]])
// NNZ = 1e6, M = N = 8192, K = 128, fp32. Indices arrive as int32 per harness.
//
// Plan:
//  1) transpose mat2 [K,N] -> mat2T [N,K] in d_ws so column gathers become
//     contiguous 512B row reads (avoids 32x overfetch of strided columns).
//  2) 16 lanes cooperate per nnz: coalesced 512B loads of the mat1 row and
//     mat2T row, dot in registers, shfl_xor reduce within the 16-lane group.

#define KDIM 128

__global__ __launch_bounds__(256) void transpose_kernel(
    const float* __restrict__ in, float* __restrict__ out, int K, int N) {
  // in: [K, N] row-major -> out: [N, K] row-major. 32x32 tiles, LDS padded.
  __shared__ float tile[32][33];
  int bx = blockIdx.x * 32;
  int by = blockIdx.y * 32;
  int tx = threadIdx.x;      // 0..31
  int ty = threadIdx.y;      // 0..7
#pragma unroll
  for (int j = 0; j < 32; j += 8) {
    tile[ty + j][tx] = in[(size_t)(by + ty + j) * N + (bx + tx)];
  }
  __syncthreads();
#pragma unroll
  for (int j = 0; j < 32; j += 8) {
    out[(size_t)(bx + ty + j) * K + (by + tx)] = tile[tx][ty + j];
  }
}

__global__ __launch_bounds__(256) void sddmm16_kernel(
    const float* __restrict__ mask_vals,
    const int* __restrict__ rows,
    const int* __restrict__ cols,
    const float* __restrict__ mat1,    // [M, 128]
    const float* __restrict__ mat2t,   // [N, 128]
    float* __restrict__ out, int nnz) {
  int tid = blockIdx.x * 256 + threadIdx.x;
  int g = tid >> 4;       // 16 lanes per nnz
  int lane = tid & 15;
  if (g >= nnz) return;

  int r = rows[g];        // group-uniform broadcast load
  int c = cols[g];

  const float4* a = (const float4*)(mat1 + (size_t)r * KDIM) + lane;
  const float4* b = (const float4*)(mat2t + (size_t)c * KDIM) + lane;
  // 16 lanes x (2 float4) = 128 floats: fully coalesced 512B per row.
  float4 a0 = a[0];
  float4 a1 = a[16];
  float4 b0 = b[0];
  float4 b1 = b[16];

  float s = a0.x * b0.x + a0.y * b0.y + a0.z * b0.z + a0.w * b0.w
          + a1.x * b1.x + a1.y * b1.y + a1.z * b1.z + a1.w * b1.w;

  // Reduce within the 16-lane group (xor masks < 16 stay inside the group).
  s += __shfl_xor(s, 8);
  s += __shfl_xor(s, 4);
  s += __shfl_xor(s, 2);
  s += __shfl_xor(s, 1);

  if (lane == 0) out[g] = mask_vals[g] + s;
}

// Fallback if d_ws can't hold the 4 MiB transpose: strided column reads.
__global__ __launch_bounds__(256) void sddmm16_strided_kernel(
    const float* __restrict__ mask_vals,
    const int* __restrict__ rows,
    const int* __restrict__ cols,
    const float* __restrict__ mat1,    // [M, 128]
    const float* __restrict__ mat2,    // [128, N]
    float* __restrict__ out, int nnz, int N) {
  int tid = blockIdx.x * 256 + threadIdx.x;
  int g = tid >> 4;
  int lane = tid & 15;
  if (g >= nnz) return;

  int r = rows[g];
  int c = cols[g];
  const float* arow = mat1 + (size_t)r * KDIM;
  float s = 0.f;
#pragma unroll
  for (int j = 0; j < 8; ++j) {
    int k = lane + 16 * j;
    s += arow[k] * mat2[(size_t)k * N + c];
  }
  s += __shfl_xor(s, 8);
  s += __shfl_xor(s, 4);
  s += __shfl_xor(s, 2);
  s += __shfl_xor(s, 1);
  if (lane == 0) out[g] = mask_vals[g] + s;
}

extern "C" void kernel_launch(void* const* d_in, const int* in_sizes, int n_in,
                              void* d_out, int out_size, void* d_ws, size_t ws_size,
                              hipStream_t stream) {
  const float* mask_vals = (const float*)d_in[0];
  const int*   rows      = (const int*)d_in[1];
  const int*   cols      = (const int*)d_in[2];
  const float* mat1      = (const float*)d_in[3];
  const float* mat2      = (const float*)d_in[4];
  float*       out       = (float*)d_out;

  int nnz = in_sizes[0];
  int N   = in_sizes[4] / KDIM;   // mat2 is [K=128, N]

  const int groups_per_block = 256 / 16;
  int blocks = (nnz + groups_per_block - 1) / groups_per_block;

  size_t needed = (size_t)KDIM * N * sizeof(float);
  if (ws_size >= needed) {
    float* mat2t = (float*)d_ws;
    dim3 tb(32, 8);
    dim3 tg(N / 32, KDIM / 32);
    transpose_kernel<<<tg, tb, 0, stream>>>(mat2, mat2t, KDIM, N);
    sddmm16_kernel<<<blocks, 256, 0, stream>>>(mask_vals, rows, cols, mat1,
                                               mat2t, out, nnz);
  } else {
    sddmm16_strided_kernel<<<blocks, 256, 0, stream>>>(mask_vals, rows, cols,
                                                       mat1, mat2, out, nnz, N);
  }
}

// Round 2
// 121.388 us; speedup vs baseline: 1.2438x; 1.2438x over previous
//
#include <hip/hip_runtime.h>
#include <hip/hip_fp16.h>

// SDDMM: out[n] = mask_vals[n] + dot(mat1[rows[n], :], mat2[:, cols[n]])
// NNZ = 1e6, M = N = 8192, K = 128, fp32 in/out.
//
// R1 post-mortem: fp32 gather working set (8 MB) > 4 MiB per-XCD L2 ->
// 277 MB L2-miss traffic at ~3.6 TB/s == the entire 80 us runtime.
// R2: convert mat1 and mat2^T to fp16 (4 MB total, L2-resident per XCD).
// Gather demand halves; L2 misses drop to compulsory fills. fp16 adds
// ~0.01-0.06 absmax error vs 1.27 threshold (values ~N(0,1), K=128).

#define KDIM 128

typedef _Float16 half2v __attribute__((ext_vector_type(2)));

union F4H8 {
  float4 f4;
  half2v h2[4];
  _Float16 h[8];
};

// fp32 -> fp16 elementwise (same layout). n must be a multiple of 8.
__global__ __launch_bounds__(256) void convert_f16_kernel(
    const float* __restrict__ in, _Float16* __restrict__ out, int n) {
  int i = (blockIdx.x * 256 + threadIdx.x) * 8;
  if (i >= n) return;
  const float4* p = (const float4*)(in + i);
  float4 x0 = p[0];
  float4 x1 = p[1];
  F4H8 o;
  o.h[0] = (_Float16)x0.x; o.h[1] = (_Float16)x0.y;
  o.h[2] = (_Float16)x0.z; o.h[3] = (_Float16)x0.w;
  o.h[4] = (_Float16)x1.x; o.h[5] = (_Float16)x1.y;
  o.h[6] = (_Float16)x1.z; o.h[7] = (_Float16)x1.w;
  *(float4*)(out + i) = o.f4;
}

// mat2 [128, N] fp32 -> mat2t [N, 128] fp16. 32x32 tiles via padded LDS.
__global__ __launch_bounds__(256) void transpose_f16_kernel(
    const float* __restrict__ in, _Float16* __restrict__ out, int N) {
  __shared__ float tile[32][33];
  int bx = blockIdx.x * 32;  // N dimension
  int by = blockIdx.y * 32;  // K dimension
  int tx = threadIdx.x;      // 0..31
  int ty = threadIdx.y;      // 0..7
#pragma unroll
  for (int j = 0; j < 32; j += 8) {
    tile[ty + j][tx] = in[(size_t)(by + ty + j) * N + (bx + tx)];
  }
  __syncthreads();
#pragma unroll
  for (int j = 0; j < 32; j += 8) {
    out[(size_t)(bx + ty + j) * KDIM + (by + tx)] = (_Float16)tile[tx][ty + j];
  }
}

__global__ __launch_bounds__(256) void sddmm_f16_kernel(
    const float* __restrict__ mask_vals,
    const int* __restrict__ rows,
    const int* __restrict__ cols,
    const _Float16* __restrict__ m1,   // [M, 128] fp16
    const _Float16* __restrict__ m2t,  // [N, 128] fp16
    float* __restrict__ out, int nnz) {
  int tid = blockIdx.x * 256 + threadIdx.x;
  int g = tid >> 4;  // 16 lanes per nnz
  int lane = tid & 15;
  if (g >= nnz) return;

  int r = rows[g];  // group-uniform broadcast loads
  int c = cols[g];

  // 16 lanes x 16 B = 256 B = one full fp16 row, fully coalesced.
  F4H8 a, b;
  a.f4 = ((const float4*)(m1 + (size_t)r * KDIM))[lane];
  b.f4 = ((const float4*)(m2t + (size_t)c * KDIM))[lane];

  float s = 0.f;
#if __has_builtin(__builtin_amdgcn_fdot2)
#pragma unroll
  for (int j = 0; j < 4; ++j) {
    s = __builtin_amdgcn_fdot2(a.h2[j], b.h2[j], s, false);
  }
#else
#pragma unroll
  for (int j = 0; j < 8; ++j) {
    s += (float)a.h[j] * (float)b.h[j];
  }
#endif

  s += __shfl_xor(s, 8);
  s += __shfl_xor(s, 4);
  s += __shfl_xor(s, 2);
  s += __shfl_xor(s, 1);

  if (lane == 0) out[g] = mask_vals[g] + s;
}

// Fallback (ws too small): fp32 strided column reads, correct but slow.
__global__ __launch_bounds__(256) void sddmm16_strided_kernel(
    const float* __restrict__ mask_vals,
    const int* __restrict__ rows,
    const int* __restrict__ cols,
    const float* __restrict__ mat1,
    const float* __restrict__ mat2,
    float* __restrict__ out, int nnz, int N) {
  int tid = blockIdx.x * 256 + threadIdx.x;
  int g = tid >> 4;
  int lane = tid & 15;
  if (g >= nnz) return;
  int r = rows[g];
  int c = cols[g];
  const float* arow = mat1 + (size_t)r * KDIM;
  float s = 0.f;
#pragma unroll
  for (int j = 0; j < 8; ++j) {
    int k = lane + 16 * j;
    s += arow[k] * mat2[(size_t)k * N + c];
  }
  s += __shfl_xor(s, 8);
  s += __shfl_xor(s, 4);
  s += __shfl_xor(s, 2);
  s += __shfl_xor(s, 1);
  if (lane == 0) out[g] = mask_vals[g] + s;
}

extern "C" void kernel_launch(void* const* d_in, const int* in_sizes, int n_in,
                              void* d_out, int out_size, void* d_ws, size_t ws_size,
                              hipStream_t stream) {
  const float* mask_vals = (const float*)d_in[0];
  const int*   rows      = (const int*)d_in[1];
  const int*   cols      = (const int*)d_in[2];
  const float* mat1      = (const float*)d_in[3];
  const float* mat2      = (const float*)d_in[4];
  float*       out       = (float*)d_out;

  int nnz   = in_sizes[0];
  int m1_sz = in_sizes[3];        // M * 128
  int N     = in_sizes[4] / KDIM; // mat2 is [128, N]

  const int groups_per_block = 256 / 16;
  int blocks = (nnz + groups_per_block - 1) / groups_per_block;

  size_t need = (size_t)m1_sz * sizeof(_Float16)
              + (size_t)KDIM * N * sizeof(_Float16);
  if (ws_size >= need) {
    _Float16* m1h  = (_Float16*)d_ws;
    _Float16* m2th = m1h + m1_sz;

    convert_f16_kernel<<<(m1_sz / 8 + 255) / 256, 256, 0, stream>>>(
        mat1, m1h, m1_sz);
    dim3 tb(32, 8);
    dim3 tg(N / 32, KDIM / 32);
    transpose_f16_kernel<<<tg, tb, 0, stream>>>(mat2, m2th, N);

    sddmm_f16_kernel<<<blocks, 256, 0, stream>>>(mask_vals, rows, cols, m1h,
                                                 m2th, out, nnz);
  } else {
    sddmm16_strided_kernel<<<blocks, 256, 0, stream>>>(mask_vals, rows, cols,
                                                       mat1, mat2, out, nnz, N);
  }
}

// Round 3
// 100.819 us; speedup vs baseline: 1.4976x; 1.2040x over previous
//
#include <hip/hip_runtime.h>
#include <hip/hip_fp16.h>

// SDDMM: out[n] = mask_vals[n] + dot(mat1[rows[n], :], mat2[:, cols[n]])
// NNZ = 1e6, M = N = 8192, K = 128, fp32 in/out. Indices int32 per harness.
//
// R1: fp32 working set 8 MB > 4 MiB/XCD L2 -> 277 MB fabric traffic, 80 us.
// R2: fp16 (4 MB, L2-resident) -> FETCH 54 MB, 63 us, but latency-bound:
//     only 2 outstanding gathers/thread, L2 BW at 23% of ceiling.
// R3: batch 4 nnz per 16-lane group -> 8 independent float4 gathers in
//     flight per thread before any reduce; 4 interleaved shfl chains;
//     coalesced float4 out/mask access by lane 0.

#define KDIM 128
#define BATCH 4

typedef _Float16 half2v __attribute__((ext_vector_type(2)));

union F4H8 {
  float4 f4;
  half2v h2[4];
  _Float16 h[8];
};

// fp32 -> fp16 elementwise (same layout). n must be a multiple of 8.
__global__ __launch_bounds__(256) void convert_f16_kernel(
    const float* __restrict__ in, _Float16* __restrict__ out, int n) {
  int i = (blockIdx.x * 256 + threadIdx.x) * 8;
  if (i >= n) return;
  const float4* p = (const float4*)(in + i);
  float4 x0 = p[0];
  float4 x1 = p[1];
  F4H8 o;
  o.h[0] = (_Float16)x0.x; o.h[1] = (_Float16)x0.y;
  o.h[2] = (_Float16)x0.z; o.h[3] = (_Float16)x0.w;
  o.h[4] = (_Float16)x1.x; o.h[5] = (_Float16)x1.y;
  o.h[6] = (_Float16)x1.z; o.h[7] = (_Float16)x1.w;
  *(float4*)(out + i) = o.f4;
}

// mat2 [128, N] fp32 -> mat2t [N, 128] fp16. 32x32 tiles via padded LDS.
__global__ __launch_bounds__(256) void transpose_f16_kernel(
    const float* __restrict__ in, _Float16* __restrict__ out, int N) {
  __shared__ float tile[32][33];
  int bx = blockIdx.x * 32;  // N dimension
  int by = blockIdx.y * 32;  // K dimension
  int tx = threadIdx.x;      // 0..31
  int ty = threadIdx.y;      // 0..7
#pragma unroll
  for (int j = 0; j < 32; j += 8) {
    tile[ty + j][tx] = in[(size_t)(by + ty + j) * N + (bx + tx)];
  }
  __syncthreads();
#pragma unroll
  for (int j = 0; j < 32; j += 8) {
    out[(size_t)(bx + ty + j) * KDIM + (by + tx)] = (_Float16)tile[tx][ty + j];
  }
}

__device__ __forceinline__ float dot8(const F4H8& a, const F4H8& b) {
  float s = 0.f;
#if __has_builtin(__builtin_amdgcn_fdot2)
#pragma unroll
  for (int j = 0; j < 4; ++j) s = __builtin_amdgcn_fdot2(a.h2[j], b.h2[j], s, false);
#else
#pragma unroll
  for (int j = 0; j < 8; ++j) s += (float)a.h[j] * (float)b.h[j];
#endif
  return s;
}

__device__ __forceinline__ float red16(float s) {
  s += __shfl_xor(s, 8);
  s += __shfl_xor(s, 4);
  s += __shfl_xor(s, 2);
  s += __shfl_xor(s, 1);
  return s;
}

__global__ __launch_bounds__(256) void sddmm_f16_b4_kernel(
    const float* __restrict__ mask_vals,
    const int* __restrict__ rows,
    const int* __restrict__ cols,
    const _Float16* __restrict__ m1,   // [M, 128] fp16
    const _Float16* __restrict__ m2t,  // [N, 128] fp16
    float* __restrict__ out, int nnz) {
  int tid = blockIdx.x * 256 + threadIdx.x;
  int grp = tid >> 4;  // 16 lanes per group; group handles BATCH nnz
  int lane = tid & 15;
  int g0 = grp * BATCH;
  if (g0 >= nnz) return;

  if (g0 + BATCH <= nnz) {
    // Group-uniform broadcast index loads (one int4 each).
    int4 r4 = *(const int4*)(rows + g0);
    int4 c4 = *(const int4*)(cols + g0);

    // Issue all 8 independent gathers before any arithmetic (MLP = 8).
    F4H8 a0, a1, a2, a3, b0, b1, b2, b3;
    a0.f4 = ((const float4*)(m1 + (size_t)r4.x * KDIM))[lane];
    a1.f4 = ((const float4*)(m1 + (size_t)r4.y * KDIM))[lane];
    a2.f4 = ((const float4*)(m1 + (size_t)r4.z * KDIM))[lane];
    a3.f4 = ((const float4*)(m1 + (size_t)r4.w * KDIM))[lane];
    b0.f4 = ((const float4*)(m2t + (size_t)c4.x * KDIM))[lane];
    b1.f4 = ((const float4*)(m2t + (size_t)c4.y * KDIM))[lane];
    b2.f4 = ((const float4*)(m2t + (size_t)c4.z * KDIM))[lane];
    b3.f4 = ((const float4*)(m2t + (size_t)c4.w * KDIM))[lane];

    float s0 = dot8(a0, b0);
    float s1 = dot8(a1, b1);
    float s2 = dot8(a2, b2);
    float s3 = dot8(a3, b3);

    // 4 independent reduction chains; compiler interleaves the ds ops.
    s0 = red16(s0);
    s1 = red16(s1);
    s2 = red16(s2);
    s3 = red16(s3);

    if (lane == 0) {
      float4 mv = *(const float4*)(mask_vals + g0);
      float4 o;
      o.x = mv.x + s0;
      o.y = mv.y + s1;
      o.z = mv.z + s2;
      o.w = mv.w + s3;
      *(float4*)(out + g0) = o;  // coalesced: lanes 0/16/32/48 -> 64 B
    }
  } else {
    // Tail (not hit for nnz = 1e6, kept for safety).
    for (int g = g0; g < nnz; ++g) {
      int r = rows[g];
      int c = cols[g];
      F4H8 a, b;
      a.f4 = ((const float4*)(m1 + (size_t)r * KDIM))[lane];
      b.f4 = ((const float4*)(m2t + (size_t)c * KDIM))[lane];
      float s = red16(dot8(a, b));
      if (lane == 0) out[g] = mask_vals[g] + s;
    }
  }
}

// Fallback (ws too small): fp32 strided column reads, correct but slow.
__global__ __launch_bounds__(256) void sddmm16_strided_kernel(
    const float* __restrict__ mask_vals,
    const int* __restrict__ rows,
    const int* __restrict__ cols,
    const float* __restrict__ mat1,
    const float* __restrict__ mat2,
    float* __restrict__ out, int nnz, int N) {
  int tid = blockIdx.x * 256 + threadIdx.x;
  int g = tid >> 4;
  int lane = tid & 15;
  if (g >= nnz) return;
  int r = rows[g];
  int c = cols[g];
  const float* arow = mat1 + (size_t)r * KDIM;
  float s = 0.f;
#pragma unroll
  for (int j = 0; j < 8; ++j) {
    int k = lane + 16 * j;
    s += arow[k] * mat2[(size_t)k * N + c];
  }
  s = red16(s);
  if (lane == 0) out[g] = mask_vals[g] + s;
}

extern "C" void kernel_launch(void* const* d_in, const int* in_sizes, int n_in,
                              void* d_out, int out_size, void* d_ws, size_t ws_size,
                              hipStream_t stream) {
  const float* mask_vals = (const float*)d_in[0];
  const int*   rows      = (const int*)d_in[1];
  const int*   cols      = (const int*)d_in[2];
  const float* mat1      = (const float*)d_in[3];
  const float* mat2      = (const float*)d_in[4];
  float*       out       = (float*)d_out;

  int nnz   = in_sizes[0];
  int m1_sz = in_sizes[3];        // M * 128
  int N     = in_sizes[4] / KDIM; // mat2 is [128, N]

  size_t need = (size_t)m1_sz * sizeof(_Float16)
              + (size_t)KDIM * N * sizeof(_Float16);
  if (ws_size >= need) {
    _Float16* m1h  = (_Float16*)d_ws;
    _Float16* m2th = m1h + m1_sz;

    convert_f16_kernel<<<(m1_sz / 8 + 255) / 256, 256, 0, stream>>>(
        mat1, m1h, m1_sz);
    dim3 tb(32, 8);
    dim3 tg(N / 32, KDIM / 32);
    transpose_f16_kernel<<<tg, tb, 0, stream>>>(mat2, m2th, N);

    int groups = (nnz + BATCH - 1) / BATCH;
    int blocks = (groups * 16 + 255) / 256;
    sddmm_f16_b4_kernel<<<blocks, 256, 0, stream>>>(mask_vals, rows, cols,
                                                    m1h, m2th, out, nnz);
  } else {
    int blocks = (nnz * 16 + 255) / 256;
    sddmm16_strided_kernel<<<blocks, 256, 0, stream>>>(mask_vals, rows, cols,
                                                       mat1, mat2, out, nnz, N);
  }
}